// Round 4
// baseline (144.359 us; speedup 1.0000x reference)
//
#include <hip/hip_runtime.h>
#include <hip/hip_bf16.h>
#include <stdint.h>

#define B_DIM 8
#define C_DIM 512
#define N_DIM 3136
#define NP    3200   // N padded to 25*128
#define BK    64
#define NT    25     // NP/128
#define NTRI  (NT * (NT + 1) / 2)  // 325 lower-tri block tiles

typedef short bf16x8 __attribute__((ext_vector_type(8)));
typedef float f32x4  __attribute__((ext_vector_type(4)));

__device__ __forceinline__ void gload16(const void* g, void* l) {
  __builtin_amdgcn_global_load_lds(
      (const __attribute__((address_space(1))) void*)g,
      (__attribute__((address_space(3))) void*)l, 16, 0, 0);
}

__device__ __forceinline__ float bf2f(ushort u) {
  union { uint32_t i; float f; } c;
  c.i = ((uint32_t)u) << 16;
  return c.f;
}

__device__ __forceinline__ ushort f2bf(float f) {
  __hip_bfloat16 h = __float2bfloat16(f);
  return *(ushort*)&h;
}

// x[b][c][n] f32 -> kt[b][n][c] bf16 (n padded to NP, pad rows zero).
__global__ __launch_bounds__(256) void k_transpose(const float* __restrict__ x,
                                                   ushort* __restrict__ kt) {
  __shared__ float tile[64][33];  // [c_local][n_local]
  const int b  = blockIdx.z;
  const int n0 = blockIdx.x * 32;
  const int c0 = blockIdx.y * 64;
  const int tx = threadIdx.x;  // 32 (n)
  const int ty = threadIdx.y;  // 8  (c)
#pragma unroll
  for (int j = 0; j < 8; ++j) {
    int c = c0 + ty + 8 * j;
    int n = n0 + tx;
    float v = (n < N_DIM) ? x[((size_t)b * C_DIM + c) * N_DIM + n] : 0.0f;
    tile[ty + 8 * j][tx] = v;
  }
  __syncthreads();
  const int tid = ty * 32 + tx;
  const int r = tid >> 5;   // n-sub 0..7
  const int p = tid & 31;   // c-pair 0..31
#pragma unroll
  for (int i = 0; i < 4; ++i) {
    int nl = r + 8 * i;
    int n = n0 + nl;
    uint32_t u = (uint32_t)f2bf(tile[2 * p][nl]) |
                 ((uint32_t)f2bf(tile[2 * p + 1][nl]) << 16);
    *(uint32_t*)(kt + ((size_t)b * NP + n) * C_DIM + c0 + 2 * p) = u;
  }
}

// sq[b*NP+n] = sum_c kt[b][n][c]^2 (fp32 accum over bf16 values).
__global__ __launch_bounds__(256) void k_norms(const ushort* __restrict__ kt,
                                               float* __restrict__ sq) {
  const int row  = blockIdx.x * 4 + (threadIdx.x >> 6);
  const int lane = threadIdx.x & 63;
  const ushort* p = kt + (size_t)row * C_DIM + lane * 8;
  bf16x8 v = *(const bf16x8*)p;
  float s = 0.0f;
#pragma unroll
  for (int j = 0; j < 8; ++j) {
    float f = bf2f((ushort)v[j]);
    s += f * f;
  }
#pragma unroll
  for (int m = 32; m >= 1; m >>= 1) s += __shfl_xor(s, m);
  if (lane == 0) sq[row] = s;
}

// Symmetric GEMM, lower-tri tiles. BK=64 main loop (8 K-steps); ALL output
// stores are dwordx4 via LDS transpose passes (direct + mirror).
__global__ __launch_bounds__(256) void k_gemm(const ushort* __restrict__ kt,
                                              const float* __restrict__ sq,
                                              float* __restrict__ out) {
  // union: staging 2x16KB during main loop; 64x132 f32 epilogue buffer
  __shared__ __attribute__((aligned(16))) char smem[64 * 132 * 4];
  ushort* tA = (ushort*)smem;             // [128][64] bf16, 16 KB
  ushort* tB = (ushort*)(smem + 16384);   // [128][64] bf16, 16 KB
  float*  tr = (float*)smem;              // [64][132] f32 (epilogue)

  const int id = blockIdx.x;
  const int b = id & 7;        // batch -> XCD round-robin (neutral, harmless)
  const int t = id >> 3;       // triangular tile index 0..324
  int bx = (int)((sqrtf(8.0f * (float)t + 1.0f) - 1.0f) * 0.5f);
  while ((bx + 1) * (bx + 2) / 2 <= t) ++bx;
  while (bx * (bx + 1) / 2 > t) --bx;
  const int by = t - bx * (bx + 1) / 2;

  const int n0 = bx * 128;  // rows (A tile)
  const int m0 = by * 128;  // cols (B tile)
  const int tid  = threadIdx.x;
  const int wave = tid >> 6;
  const int lane = tid & 63;
  const ushort* ktb = kt + (size_t)b * NP * C_DIM;

  const int wr = (wave >> 1) * 64;
  const int wc = (wave & 1) * 64;
  const int koff = lane >> 4;
  const int rl = lane & 15;

  f32x4 acc[4][4];
#pragma unroll
  for (int mi = 0; mi < 4; ++mi)
#pragma unroll
    for (int ni = 0; ni < 4; ++ni)
      acc[mi][ni] = (f32x4){0.f, 0.f, 0.f, 0.f};

  for (int ks = 0; ks < C_DIM / BK; ++ks) {
    __syncthreads();
    const int kbase = ks * BK;
    // stage 128x64 bf16 per operand: 1024 16B-chunks each, 8 gloads/thread.
    // LDS linear; source pre-swizzled: logical chunk lk = phys ^ (row&7).
#pragma unroll
    for (int i = 0; i < 4; ++i) {
      int q   = i * 256 + wave * 64 + lane;   // chunk 0..1023
      int row = q >> 3;
      int lk  = (q & 7) ^ ((q >> 3) & 7);
      const ushort* gA = ktb + (size_t)(n0 + row) * C_DIM + kbase + lk * 8;
      const ushort* gB = ktb + (size_t)(m0 + row) * C_DIM + kbase + lk * 8;
      char* lA = (char*)tA + (i * 256 + wave * 64) * 16;  // wave-uniform base
      char* lB = (char*)tB + (i * 256 + wave * 64) * 16;
      gload16(gA, lA);
      gload16(gB, lB);
    }
    __syncthreads();

#pragma unroll
    for (int s = 0; s < 2; ++s) {
      bf16x8 aF[4], bF[4];
#pragma unroll
      for (int mi = 0; mi < 4; ++mi) {
        int row  = wr + mi * 16 + rl;
        int phys = (s * 4 + koff) ^ (row & 7);
        aF[mi] = *(const bf16x8*)((const char*)tA + row * 128 + phys * 16);
      }
#pragma unroll
      for (int ni = 0; ni < 4; ++ni) {
        int row  = wc + ni * 16 + rl;
        int phys = (s * 4 + koff) ^ (row & 7);
        bF[ni] = *(const bf16x8*)((const char*)tB + row * 128 + phys * 16);
      }
#pragma unroll
      for (int mi = 0; mi < 4; ++mi)
#pragma unroll
        for (int ni = 0; ni < 4; ++ni)
          acc[mi][ni] = __builtin_amdgcn_mfma_f32_16x16x32_bf16(
              aF[mi], bF[ni], acc[mi][ni], 0, 0, 0);
    }
  }

  // ---- epilogue: normalize ----
  const float* sqb = sq + b * NP;
  float rrow[4][4], rcol[4];
#pragma unroll
  for (int mi = 0; mi < 4; ++mi)
#pragma unroll
    for (int r = 0; r < 4; ++r) {
      float s = sqb[n0 + wr + mi * 16 + koff * 4 + r];
      rrow[mi][r] = 1.0f / fmaxf(sqrtf(s), 1e-8f);
    }
#pragma unroll
  for (int ni = 0; ni < 4; ++ni) {
    float s = sqb[m0 + wc + ni * 16 + rl];
    rcol[ni] = 1.0f / fmaxf(sqrtf(s), 1e-8f);
  }
#pragma unroll
  for (int mi = 0; mi < 4; ++mi)
#pragma unroll
    for (int ni = 0; ni < 4; ++ni)
#pragma unroll
      for (int r = 0; r < 4; ++r)
        acc[mi][ni][r] *= rrow[mi][r] * rcol[ni];

  float* outb = out + (size_t)b * N_DIM * N_DIM;

  // direct write via LDS row-major transpose -> dwordx4 stores.
  // pass dh: rows dh*64..dh*64+63 (owned by waves with wr==dh*64)
#pragma unroll
  for (int dh = 0; dh < 2; ++dh) {
    __syncthreads();
    if ((wave >> 1) == dh) {
#pragma unroll
      for (int mi = 0; mi < 4; ++mi)
#pragma unroll
        for (int ni = 0; ni < 4; ++ni) {
          int colL = wc + ni * 16 + rl;
#pragma unroll
          for (int r = 0; r < 4; ++r) {
            int rowL = mi * 16 + koff * 4 + r;
            tr[rowL * 132 + colL] = acc[mi][ni][r];
          }
        }
    }
    __syncthreads();
#pragma unroll
    for (int it = 0; it < 8; ++it) {
      int i  = it * 8 + (tid >> 5);   // local row 0..63
      int j4 = (tid & 31) * 4;        // col chunk
      int row = n0 + dh * 64 + i;
      int col = m0 + j4;
      if (row < N_DIM && col < N_DIM)  // N_DIM%4==0 -> chunk-safe
        *(f32x4*)(outb + (size_t)row * N_DIM + col) =
            *(const f32x4*)(tr + i * 132 + j4);
    }
  }

  // mirror write: out[m0+col][n0+row] via LDS col-major transpose
  if (bx != by) {
#pragma unroll
    for (int h = 0; h < 2; ++h) {
      __syncthreads();
      if ((wave & 1) == h) {
#pragma unroll
        for (int ni = 0; ni < 4; ++ni) {
          int colL = ni * 16 + rl;  // 0..63
#pragma unroll
          for (int mi = 0; mi < 4; ++mi) {
            int row = wr + mi * 16 + koff * 4;  // 16B-aligned
            *(f32x4*)(tr + colL * 132 + row) = acc[mi][ni];
          }
        }
      }
      __syncthreads();
#pragma unroll
      for (int it = 0; it < 8; ++it) {
        int i  = it * 8 + (tid >> 5);
        int j4 = (tid & 31) * 4;
        int gm = m0 + h * 64 + i;       // global row (= original col)
        int gn = n0 + j4;               // global col (= original row)
        if (gm < N_DIM && gn < N_DIM) {
          f32x4 v = *(const f32x4*)(tr + i * 132 + j4);
          *(f32x4*)(outb + (size_t)gm * N_DIM + gn) = v;
        }
      }
    }
  }
}

extern "C" void kernel_launch(void* const* d_in, const int* in_sizes, int n_in,
                              void* d_out, int out_size, void* d_ws, size_t ws_size,
                              hipStream_t stream) {
  const float* x = (const float*)d_in[0];
  float* out = (float*)d_out;

  ushort* kt = (ushort*)d_ws;
  float* sq = (float*)((char*)d_ws + (size_t)B_DIM * NP * C_DIM * 2);

  dim3 gT(NP / 32, C_DIM / 64, B_DIM);  // 100,8,8
  k_transpose<<<gT, dim3(32, 8), 0, stream>>>(x, kt);

  k_norms<<<B_DIM * NP / 4, 256, 0, stream>>>(kt, sq);

  k_gemm<<<NTRI * B_DIM, 256, 0, stream>>>(kt, sq, out);  // 2600 blocks
}

// Round 5
// 138.034 us; speedup vs baseline: 1.0458x; 1.0458x over previous
//
#include <hip/hip_runtime.h>
#include <hip/hip_bf16.h>
#include <stdint.h>

#define B_DIM 8
#define C_DIM 512
#define N_DIM 3136
#define NP    3200   // N padded to 25*128
#define BK    32
#define NKS   (C_DIM / BK)         // 16 K-steps
#define NT    25                   // NP/128
#define NTRI  (NT * (NT + 1) / 2)  // 325 lower-tri block tiles

typedef short bf16x8 __attribute__((ext_vector_type(8)));
typedef float f32x4  __attribute__((ext_vector_type(4)));

__device__ __forceinline__ void gload16(const void* g, void* l) {
  __builtin_amdgcn_global_load_lds(
      (const __attribute__((address_space(1))) void*)g,
      (__attribute__((address_space(3))) void*)l, 16, 0, 0);
}

__device__ __forceinline__ float bf2f(ushort u) {
  union { uint32_t i; float f; } c;
  c.i = ((uint32_t)u) << 16;
  return c.f;
}

__device__ __forceinline__ ushort f2bf(float f) {
  __hip_bfloat16 h = __float2bfloat16(f);
  return *(ushort*)&h;
}

// x[b][c][n] f32 -> kt[b][n][c] bf16 (n padded to NP, pad rows zero).
__global__ __launch_bounds__(256) void k_transpose(const float* __restrict__ x,
                                                   ushort* __restrict__ kt) {
  __shared__ float tile[64][33];  // [c_local][n_local]
  const int b  = blockIdx.z;
  const int n0 = blockIdx.x * 32;
  const int c0 = blockIdx.y * 64;
  const int tx = threadIdx.x;  // 32 (n)
  const int ty = threadIdx.y;  // 8  (c)
#pragma unroll
  for (int j = 0; j < 8; ++j) {
    int c = c0 + ty + 8 * j;
    int n = n0 + tx;
    float v = (n < N_DIM) ? x[((size_t)b * C_DIM + c) * N_DIM + n] : 0.0f;
    tile[ty + 8 * j][tx] = v;
  }
  __syncthreads();
  const int tid = ty * 32 + tx;
  const int r = tid >> 5;   // n-sub 0..7
  const int p = tid & 31;   // c-pair 0..31
#pragma unroll
  for (int i = 0; i < 4; ++i) {
    int nl = r + 8 * i;
    int n = n0 + nl;
    uint32_t u = (uint32_t)f2bf(tile[2 * p][nl]) |
                 ((uint32_t)f2bf(tile[2 * p + 1][nl]) << 16);
    *(uint32_t*)(kt + ((size_t)b * NP + n) * C_DIM + c0 + 2 * p) = u;
  }
}

// sq[b*NP+n] = sum_c kt[b][n][c]^2 (fp32 accum over bf16 values).
__global__ __launch_bounds__(256) void k_norms(const ushort* __restrict__ kt,
                                               float* __restrict__ sq) {
  const int row  = blockIdx.x * 4 + (threadIdx.x >> 6);
  const int lane = threadIdx.x & 63;
  const ushort* p = kt + (size_t)row * C_DIM + lane * 8;
  bf16x8 v = *(const bf16x8*)p;
  float s = 0.0f;
#pragma unroll
  for (int j = 0; j < 8; ++j) {
    float f = bf2f((ushort)v[j]);
    s += f * f;
  }
#pragma unroll
  for (int m = 32; m >= 1; m >>= 1) s += __shfl_xor(s, m);
  if (lane == 0) sq[row] = s;
}

// Symmetric GEMM, lower-tri tiles. 2-phase double-buffered main loop:
// per K-step issue next tile's global_load_lds BEFORE computing current
// tile, one barrier(+drain) per step -> HBM/L2 latency hides under
// ds_read+MFMA. Epilogue: coalesced scalar direct stores + LDS-transposed
// mirror (round-3 proven).
__global__ __launch_bounds__(256) void k_gemm(const ushort* __restrict__ kt,
                                              const float* __restrict__ sq,
                                              float* __restrict__ out) {
  // union: 2 staging buffers (2 x (tA 8KB + tB 8KB) = 32 KB) in main loop;
  // 64x132 f32 transpose buffer (33.8 KB) in mirror epilogue.
  __shared__ __attribute__((aligned(16))) char smem[64 * 132 * 4];
  float* tr = (float*)smem;

  const int id = blockIdx.x;
  const int b = id & 7;        // batch -> XCD round-robin
  const int t = id >> 3;       // triangular tile index 0..324
  int bx = (int)((sqrtf(8.0f * (float)t + 1.0f) - 1.0f) * 0.5f);
  while ((bx + 1) * (bx + 2) / 2 <= t) ++bx;
  while (bx * (bx + 1) / 2 > t) --bx;
  const int by = t - bx * (bx + 1) / 2;

  const int n0 = bx * 128;  // rows (A tile)
  const int m0 = by * 128;  // cols (B tile)
  const int tid  = threadIdx.x;
  const int wave = tid >> 6;
  const int lane = tid & 63;
  const ushort* ktb = kt + (size_t)b * NP * C_DIM;

  const int wr = (wave >> 1) * 64;
  const int wc = (wave & 1) * 64;
  const int koff = lane >> 4;
  const int rl = lane & 15;

  // per-thread staging addresses (invariant across K-steps except kbase)
  const int q   = wave * 64 + lane;          // base chunk this thread covers
  const int row0 = q >> 2;
  const int lk0  = (q & 3) ^ ((q >> 3) & 3); // pre-swizzled source chunk
  const int row1 = (q + 256) >> 2;
  const int lk1  = (q & 3) ^ (((q + 256) >> 3) & 3);
  const ushort* gA0 = ktb + (size_t)(n0 + row0) * C_DIM + lk0 * 8;
  const ushort* gA1 = ktb + (size_t)(n0 + row1) * C_DIM + lk1 * 8;
  const ushort* gB0 = ktb + (size_t)(m0 + row0) * C_DIM + lk0 * 8;
  const ushort* gB1 = ktb + (size_t)(m0 + row1) * C_DIM + lk1 * 8;
  const int ldOff0 = q * 16;            // byte offset within a staging tile
  const int ldOff1 = (q + 256) * 16;

  f32x4 acc[4][4];
#pragma unroll
  for (int mi = 0; mi < 4; ++mi)
#pragma unroll
    for (int ni = 0; ni < 4; ++ni)
      acc[mi][ni] = (f32x4){0.f, 0.f, 0.f, 0.f};

#define STAGE(ksi, buf)                                                     \
  do {                                                                      \
    const int kb = (ksi) * BK;                                              \
    char* base = smem + (buf) * 16384;                                      \
    gload16(gA0 + kb, base + ldOff0);                                       \
    gload16(gA1 + kb, base + ldOff1);                                       \
    gload16(gB0 + kb, base + 8192 + ldOff0);                                \
    gload16(gB1 + kb, base + 8192 + ldOff1);                                \
  } while (0)

  STAGE(0, 0);
  __syncthreads();  // drain prologue loads

  for (int ks = 0; ks < NKS; ++ks) {
    const int cur = ks & 1;
    if (ks + 1 < NKS) STAGE(ks + 1, cur ^ 1);  // prefetch next (in flight)

    const ushort* tA = (const ushort*)(smem + cur * 16384);
    const ushort* tB = (const ushort*)(smem + cur * 16384 + 8192);
    bf16x8 aF[4], bF[4];
#pragma unroll
    for (int mi = 0; mi < 4; ++mi) {
      int row  = wr + mi * 16 + rl;
      int phys = koff ^ ((row >> 1) & 3);
      aF[mi] = *(const bf16x8*)((const char*)tA + row * 64 + phys * 16);
    }
#pragma unroll
    for (int ni = 0; ni < 4; ++ni) {
      int row  = wc + ni * 16 + rl;
      int phys = koff ^ ((row >> 1) & 3);
      bF[ni] = *(const bf16x8*)((const char*)tB + row * 64 + phys * 16);
    }
#pragma unroll
    for (int mi = 0; mi < 4; ++mi)
#pragma unroll
      for (int ni = 0; ni < 4; ++ni)
        acc[mi][ni] = __builtin_amdgcn_mfma_f32_16x16x32_bf16(
            aF[mi], bF[ni], acc[mi][ni], 0, 0, 0);

    __syncthreads();  // full drain: next buffer complete, this buffer free
  }
#undef STAGE

  // ---- epilogue: normalize ----
  const float* sqb = sq + b * NP;
  float rrow[4][4], rcol[4];
#pragma unroll
  for (int mi = 0; mi < 4; ++mi)
#pragma unroll
    for (int r = 0; r < 4; ++r) {
      float s = sqb[n0 + wr + mi * 16 + koff * 4 + r];
      rrow[mi][r] = 1.0f / fmaxf(sqrtf(s), 1e-8f);
    }
#pragma unroll
  for (int ni = 0; ni < 4; ++ni) {
    float s = sqb[m0 + wc + ni * 16 + rl];
    rcol[ni] = 1.0f / fmaxf(sqrtf(s), 1e-8f);
  }
#pragma unroll
  for (int mi = 0; mi < 4; ++mi)
#pragma unroll
    for (int ni = 0; ni < 4; ++ni)
#pragma unroll
      for (int r = 0; r < 4; ++r)
        acc[mi][ni][r] *= rrow[mi][r] * rcol[ni];

  float* outb = out + (size_t)b * N_DIM * N_DIM;

  // direct write: out[n0+row][m0+col] — 4x64B segments per wave-store, fine
#pragma unroll
  for (int mi = 0; mi < 4; ++mi) {
#pragma unroll
    for (int ni = 0; ni < 4; ++ni) {
#pragma unroll
      for (int r = 0; r < 4; ++r) {
        int row = n0 + wr + mi * 16 + koff * 4 + r;
        int col = m0 + wc + ni * 16 + rl;
        if (row < N_DIM && col < N_DIM)
          outb[(size_t)row * N_DIM + col] = acc[mi][ni][r];
      }
    }
  }

  // mirror write: out[m0+col][n0+row] via LDS transpose, two 64-col passes
  if (bx != by) {
#pragma unroll
    for (int h = 0; h < 2; ++h) {
      __syncthreads();
      if ((wave & 1) == h) {
#pragma unroll
        for (int ni = 0; ni < 4; ++ni) {
          int colL = ni * 16 + rl;  // 0..63
#pragma unroll
          for (int mi = 0; mi < 4; ++mi) {
            int row = wr + mi * 16 + koff * 4;  // 16B-aligned
            *(f32x4*)(tr + colL * 132 + row) = acc[mi][ni];
          }
        }
      }
      __syncthreads();
#pragma unroll
      for (int it = 0; it < 8; ++it) {
        int i  = it * 8 + (tid >> 5);   // local mirror row 0..63
        int j4 = (tid & 31) * 4;        // col chunk
        int gm = m0 + h * 64 + i;       // global row (= original col)
        int gn = n0 + j4;               // global col (= original row)
        if (gm < N_DIM && gn < N_DIM) {
          f32x4 v = *(const f32x4*)(tr + i * 132 + j4);
          *(f32x4*)(outb + (size_t)gm * N_DIM + gn) = v;
        }
      }
    }
  }
}

extern "C" void kernel_launch(void* const* d_in, const int* in_sizes, int n_in,
                              void* d_out, int out_size, void* d_ws, size_t ws_size,
                              hipStream_t stream) {
  const float* x = (const float*)d_in[0];
  float* out = (float*)d_out;

  ushort* kt = (ushort*)d_ws;
  float* sq = (float*)((char*)d_ws + (size_t)B_DIM * NP * C_DIM * 2);

  dim3 gT(NP / 32, C_DIM / 64, B_DIM);  // 100,8,8
  k_transpose<<<gT, dim3(32, 8), 0, stream>>>(x, kt);

  k_norms<<<B_DIM * NP / 4, 256, 0, stream>>>(kt, sq);

  k_gemm<<<NTRI * B_DIM, 256, 0, stream>>>(kt, sq, out);  // 2600 blocks
}